// Round 11
// baseline (31.982 us; speedup 1.0000x reference)
//
#include <hip/hip_runtime.h>
#include <hip/hip_fp16.h>

// Joint bilateral filter, K=5, zero padding. R10 body (shifted LDS layout,
// 8-wide aligned windows) + PERSISTENT BLOCKS: grid = 1280 = 5 blocks/CU
// (the LDS residency capacity), each block strides over the 1800 tiles.
// Fixes the 1.4-scheduling-round under-fill (R10 avg occupancy 27% vs 62%
// static limit): all CUs stay at 20 waves/CU until the drain tail.
// t: (2,3,720,1280) f32; v: (2,2,720,1280) f32; out: (2,2,720,1280) f32
// coeff = max(0.875 - 50*sum_c (t_c - ts_c)^2, 0); out = sum(vs*coeff)/sum(coeff)

constexpr int H_ = 720;
constexpr int W_ = 1280;
constexpr int HW = H_ * W_;
constexpr float COEF0 = 0.875f;  // 1 - |NEG_SS_DIV|
constexpr float SIDIV = 50.0f;   // 1/(2*0.1^2)

constexpr int TC = 132;          // staged cols: global gx0-2 .. gx0+129
constexpr int TR = 12;           // staged rows: gy0-2 .. gy0+9
constexpr int NK = 34;           // aligned global chunks per row (gx0-4+4k)
constexpr int NCHUNK = 5 * TR * NK;   // 2040
constexpr int NTILES = 1800;
constexpr int GRID = 1280;       // 5 blocks/CU * 256 CUs

// load one staged row's 8-wide windows (5 channels) into FRESH arrays in scope
#define LOADW(LR)                                                              \
    float w0[8], w1[8], w2[8], u0[8], u1[8];                                   \
    _Pragma("unroll") for (int s_ = 0; s_ < 2; ++s_) {                         \
        *(float4*)(w0 + 4 * s_) = *(const float4*)&lds[0][LR][lc + 4 * s_];    \
        *(float4*)(w1 + 4 * s_) = *(const float4*)&lds[1][LR][lc + 4 * s_];    \
        *(float4*)(w2 + 4 * s_) = *(const float4*)&lds[2][LR][lc + 4 * s_];    \
        *(float4*)(u0 + 4 * s_) = *(const float4*)&lds[3][LR][lc + 4 * s_];    \
        *(float4*)(u1 + 4 * s_) = *(const float4*)&lds[4][LR][lc + 4 * s_];    \
    }

// accumulate 5x4 taps; window elem m <-> global col x0w+m, tap k = dx+j in [0,7]
#define COMPW()                                                                \
    _Pragma("unroll") for (int dx_ = 0; dx_ < 5; ++dx_)                        \
        _Pragma("unroll") for (int j_ = 0; j_ < 4; ++j_) {                     \
            const int k_ = dx_ + j_;                                           \
            const float d0_ = c0f[j_] - w0[k_];                                \
            const float d1_ = c1f[j_] - w1[k_];                                \
            const float d2_ = c2f[j_] - w2[k_];                                \
            float diff_ = d0_ * d0_;                                           \
            diff_ = fmaf(d1_, d1_, diff_);                                     \
            diff_ = fmaf(d2_, d2_, diff_);                                     \
            const float c_ = fmaxf(fmaf(diff_, -SIDIV, COEF0), 0.f);           \
            num0[j_] = fmaf(u0[k_], c_, num0[j_]);                             \
            num1[j_] = fmaf(u1[k_], c_, num1[j_]);                             \
            den[j_] += c_;                                                     \
        }

__global__ __launch_bounds__(256)
void jbf_pers(const float* __restrict__ t, const float* __restrict__ v,
              float* __restrict__ out) {
    __shared__ float lds[5][TR][TC];        // 31,680 B -> 5 blocks/CU

    const int tid = threadIdx.x;
    const int tx = tid & 31;                // x-group within tile
    const int ty = tid >> 5;                // output row within tile
    const int lc = 4 * tx;                  // window base staged col

#pragma unroll 1
    for (int tile = blockIdx.x; tile < NTILES; tile += GRID) {
        const int bx = tile % 10;           // 10 x-tiles of 128
        const int by = (tile / 10) % 90;    // 90 y-tiles of 8
        const int n  = tile / 900;          // 2 images
        const int gx0 = bx * 128;
        const int gy0 = by * 8;

        const float* tn = t + (size_t)n * 3 * HW;
        const float* vn = v + (size_t)n * 2 * HW;
        float*       on = out + (size_t)n * 2 * HW;

        __syncthreads();                    // LDS safe to overwrite (no-op cost on iter 1)

        // ---- stage: aligned global float4 -> two 8B-aligned float2 LDS writes ----
#pragma unroll
        for (int it = 0; it < 8; ++it) {
            const int i = tid + it * 256;
            if (i < NCHUNK) {
                const int k  = i % NK;       // chunk: global cols gx0-4+4k..+3
                const int rr = (i / NK) % TR;
                const int ch = i / (NK * TR);   // 0..2 = t, 3..4 = v
                const int gy = gy0 - 2 + rr;
                const int gx = gx0 - 4 + 4 * k;
                float4 val = make_float4(0.f, 0.f, 0.f, 0.f);
                if ((unsigned)gy < (unsigned)H_ && (unsigned)gx < (unsigned)(W_ - 3)) {
                    const float* src = (ch < 3) ? (tn + (size_t)ch * HW)
                                                : (vn + (size_t)(ch - 3) * HW);
                    val = *(const float4*)(src + gy * W_ + gx);
                }
                // global cols gx..gx+3 <-> staged cols 4k-2 .. 4k+1
                float* row = &lds[ch][rr][0];
                if (k > 0)      *(float2*)&row[4 * k - 2] = make_float2(val.x, val.y);
                if (k < NK - 1) *(float2*)&row[4 * k]     = make_float2(val.z, val.w);
            }
        }
        __syncthreads();

        // ---------------- compute 4 px from LDS ----------------
        float c0f[4], c1f[4], c2f[4];
        float num0[4] = {0.f, 0.f, 0.f, 0.f};
        float num1[4] = {0.f, 0.f, 0.f, 0.f};
        float den[4]  = {0.f, 0.f, 0.f, 0.f};

        {   // r = 2 first: its window contains the centers (elem j+2 = pixel j)
            const int lr = ty + 2;
            LOADW(lr)
#pragma unroll
            for (int j = 0; j < 4; ++j) {
                c0f[j] = w0[j + 2];
                c1f[j] = w1[j + 2];
                c2f[j] = w2[j + 2];
            }
            COMPW()
        }
#pragma unroll 1
        for (int i = 0; i < 4; ++i) {
            const int r = i + (i >> 1);      // 0,1,3,4
            const int lr = ty + r;
            LOADW(lr)
            COMPW()
        }

        float4 o0, o1;
        float* o0a = (float*)&o0;
        float* o1a = (float*)&o1;
#pragma unroll
        for (int j = 0; j < 4; ++j) {
            const float rcp = 1.f / den[j];
            // mimic the reference's fp16 round-trip
            o0a[j] = __half2float(__float2half(num0[j] * rcp));
            o1a[j] = __half2float(__float2half(num1[j] * rcp));
        }
        const int ctr = (gy0 + ty) * W_ + gx0 + 4 * tx;
        *(float4*)(on + ctr) = o0;
        *(float4*)(on + HW + ctr) = o1;
    }
}

extern "C" void kernel_launch(void* const* d_in, const int* in_sizes, int n_in,
                              void* d_out, int out_size, void* d_ws, size_t ws_size,
                              hipStream_t stream) {
    const float* t = (const float*)d_in[0];
    const float* v = (const float*)d_in[1];
    float* out = (float*)d_out;

    // persistent: 1280 blocks = 5/CU residency capacity; each strides the 1800 tiles
    jbf_pers<<<GRID, 256, 0, stream>>>(t, v, out);
}

// Round 12
// 27.645 us; speedup vs baseline: 1.1569x; 1.1569x over previous
//
#include <hip/hip_runtime.h>
#include <hip/hip_fp16.h>

// Joint bilateral filter, K=5, zero padding. R10 body (shifted LDS layout,
// 8-wide aligned windows, best 30.9us) + XCD-AWARE TILE SWIZZLE (T1):
// 1800 blocks % 8 == 0 -> bijective wgid = (bid&7)*225 + (bid>>3).
// Each XCD gets a contiguous band of 225 tiles (~180 image rows): its L2
// fetches ~1/8 of the input once and vertical-halo re-reads become L2 hits.
// Theory: plateau rounds all show dur ~= FETCH_SIZE(100MB)/3.2TB/s -> cutting
// fetch is the only lever that should move dur.
// t: (2,3,720,1280) f32; v: (2,2,720,1280) f32; out: (2,2,720,1280) f32
// coeff = max(0.875 - 50*sum_c (t_c - ts_c)^2, 0); out = sum(vs*coeff)/sum(coeff)

constexpr int H_ = 720;
constexpr int W_ = 1280;
constexpr int HW = H_ * W_;
constexpr float COEF0 = 0.875f;  // 1 - |NEG_SS_DIV|
constexpr float SIDIV = 50.0f;   // 1/(2*0.1^2)

constexpr int TC = 132;          // staged cols: global gx0-2 .. gx0+129
constexpr int TR = 12;           // staged rows: gy0-2 .. gy0+9
constexpr int NK = 34;           // aligned global chunks per row (gx0-4+4k)
constexpr int NCHUNK = 5 * TR * NK;   // 2040
constexpr int NXCD = 8;
constexpr int CPX = 1800 / NXCD; // 225 tiles per XCD band (exact)

// load one staged row's 8-wide windows (5 channels) into FRESH arrays in scope
#define LOADW(LR)                                                              \
    float w0[8], w1[8], w2[8], u0[8], u1[8];                                   \
    _Pragma("unroll") for (int s_ = 0; s_ < 2; ++s_) {                         \
        *(float4*)(w0 + 4 * s_) = *(const float4*)&lds[0][LR][lc + 4 * s_];    \
        *(float4*)(w1 + 4 * s_) = *(const float4*)&lds[1][LR][lc + 4 * s_];    \
        *(float4*)(w2 + 4 * s_) = *(const float4*)&lds[2][LR][lc + 4 * s_];    \
        *(float4*)(u0 + 4 * s_) = *(const float4*)&lds[3][LR][lc + 4 * s_];    \
        *(float4*)(u1 + 4 * s_) = *(const float4*)&lds[4][LR][lc + 4 * s_];    \
    }

// accumulate 5x4 taps; window elem m <-> global col x0w+m, tap k = dx+j in [0,7]
#define COMPW()                                                                \
    _Pragma("unroll") for (int dx_ = 0; dx_ < 5; ++dx_)                        \
        _Pragma("unroll") for (int j_ = 0; j_ < 4; ++j_) {                     \
            const int k_ = dx_ + j_;                                           \
            const float d0_ = c0f[j_] - w0[k_];                                \
            const float d1_ = c1f[j_] - w1[k_];                                \
            const float d2_ = c2f[j_] - w2[k_];                                \
            float diff_ = d0_ * d0_;                                           \
            diff_ = fmaf(d1_, d1_, diff_);                                     \
            diff_ = fmaf(d2_, d2_, diff_);                                     \
            const float c_ = fmaxf(fmaf(diff_, -SIDIV, COEF0), 0.f);           \
            num0[j_] = fmaf(u0[k_], c_, num0[j_]);                             \
            num1[j_] = fmaf(u1[k_], c_, num1[j_]);                             \
            den[j_] += c_;                                                     \
        }

__global__ __launch_bounds__(256)
void jbf_x(const float* __restrict__ t, const float* __restrict__ v,
           float* __restrict__ out) {
    __shared__ float lds[5][TR][TC];        // 31,680 B -> 5 blocks/CU

    // ---- XCD-aware bijective swizzle: XCD i owns tiles [i*225, (i+1)*225) ----
    const int wgid = (blockIdx.x & (NXCD - 1)) * CPX + (blockIdx.x >> 3);
    const int n   = wgid / 900;             // image
    const int rem = wgid % 900;
    const int by  = rem / 10;               // tile-row (y-major band, x-major inside)
    const int bx  = rem % 10;
    const int gx0 = bx * 128;
    const int gy0 = by * 8;

    const float* tn = t + (size_t)n * 3 * HW;
    const float* vn = v + (size_t)n * 2 * HW;
    float*       on = out + (size_t)n * 2 * HW;

    const int tid = threadIdx.x;

    // ------- stage: aligned global float4 -> two 8B-aligned float2 LDS writes -------
#pragma unroll
    for (int it = 0; it < 8; ++it) {
        const int i = tid + it * 256;
        if (i < NCHUNK) {
            const int k  = i % NK;           // chunk: global cols gx0-4+4k..+3
            const int rr = (i / NK) % TR;    // staged row
            const int ch = i / (NK * TR);    // 0..2 = t, 3..4 = v
            const int gy = gy0 - 2 + rr;
            const int gx = gx0 - 4 + 4 * k;
            float4 val = make_float4(0.f, 0.f, 0.f, 0.f);
            if ((unsigned)gy < (unsigned)H_ && (unsigned)gx < (unsigned)(W_ - 3)) {
                const float* src = (ch < 3) ? (tn + (size_t)ch * HW)
                                            : (vn + (size_t)(ch - 3) * HW);
                val = *(const float4*)(src + gy * W_ + gx);
            }
            // global cols gx..gx+3 <-> staged cols 4k-2 .. 4k+1
            float* row = &lds[ch][rr][0];
            if (k > 0)      *(float2*)&row[4 * k - 2] = make_float2(val.x, val.y);
            if (k < NK - 1) *(float2*)&row[4 * k]     = make_float2(val.z, val.w);
        }
    }
    __syncthreads();

    // ---------------- compute 4 px from LDS ----------------
    const int tx = tid & 31;                 // x-group within tile
    const int ty = tid >> 5;                 // output row within tile
    const int lc = 4 * tx;                   // window base staged col

    float c0f[4], c1f[4], c2f[4];
    float num0[4] = {0.f, 0.f, 0.f, 0.f};
    float num1[4] = {0.f, 0.f, 0.f, 0.f};
    float den[4]  = {0.f, 0.f, 0.f, 0.f};

    {   // r = 2 first: its window contains the centers (elem j+2 = pixel j)
        const int lr = ty + 2;
        LOADW(lr)
#pragma unroll
        for (int j = 0; j < 4; ++j) {
            c0f[j] = w0[j + 2];
            c1f[j] = w1[j + 2];
            c2f[j] = w2[j + 2];
        }
        COMPW()
    }
#pragma unroll 1
    for (int i = 0; i < 4; ++i) {
        const int r = i + (i >> 1);          // 0,1,3,4
        const int lr = ty + r;
        LOADW(lr)
        COMPW()
    }

    float4 o0, o1;
    float* o0a = (float*)&o0;
    float* o1a = (float*)&o1;
#pragma unroll
    for (int j = 0; j < 4; ++j) {
        const float rcp = 1.f / den[j];
        // mimic the reference's fp16 round-trip
        o0a[j] = __half2float(__float2half(num0[j] * rcp));
        o1a[j] = __half2float(__float2half(num1[j] * rcp));
    }
    const int ctr = (gy0 + ty) * W_ + gx0 + 4 * tx;
    *(float4*)(on + ctr) = o0;
    *(float4*)(on + HW + ctr) = o1;
}

extern "C" void kernel_launch(void* const* d_in, const int* in_sizes, int n_in,
                              void* d_out, int out_size, void* d_ws, size_t ws_size,
                              hipStream_t stream) {
    const float* t = (const float*)d_in[0];
    const float* v = (const float*)d_in[1];
    float* out = (float*)d_out;

    // 10 x-tiles * 90 y-tiles * 2 images = 1800 blocks of 256 (XCD-swizzled)
    jbf_x<<<1800, 256, 0, stream>>>(t, v, out);
}

// Round 13
// 26.456 us; speedup vs baseline: 1.2089x; 1.0449x over previous
//
#include <hip/hip_runtime.h>
#include <hip/hip_fp16.h>

// Joint bilateral filter, K=5, zero padding. R12 (shifted LDS layout + XCD
// band swizzle, best 27.6us) + STAGING MLP: all 8 global float4 loads issue
// into named registers BEFORE any ds_write (one latency window instead of
// up-to-8 serialized load->write round trips), then one drain + 16 ds_writes.
// t: (2,3,720,1280) f32; v: (2,2,720,1280) f32; out: (2,2,720,1280) f32
// coeff = max(0.875 - 50*sum_c (t_c - ts_c)^2, 0); out = sum(vs*coeff)/sum(coeff)

constexpr int H_ = 720;
constexpr int W_ = 1280;
constexpr int HW = H_ * W_;
constexpr float COEF0 = 0.875f;  // 1 - |NEG_SS_DIV|
constexpr float SIDIV = 50.0f;   // 1/(2*0.1^2)

constexpr int TC = 132;          // staged cols: global gx0-2 .. gx0+129
constexpr int TR = 12;           // staged rows: gy0-2 .. gy0+9
constexpr int NK = 34;           // aligned global chunks per row (gx0-4+4k)
constexpr int NCHUNK = 5 * TR * NK;   // 2040
constexpr int NXCD = 8;
constexpr int CPX = 1800 / NXCD; // 225 tiles per XCD band (exact)

// load one staged row's 8-wide windows (5 channels) into FRESH arrays in scope
#define LOADW(LR)                                                              \
    float w0[8], w1[8], w2[8], u0[8], u1[8];                                   \
    _Pragma("unroll") for (int s_ = 0; s_ < 2; ++s_) {                         \
        *(float4*)(w0 + 4 * s_) = *(const float4*)&lds[0][LR][lc + 4 * s_];    \
        *(float4*)(w1 + 4 * s_) = *(const float4*)&lds[1][LR][lc + 4 * s_];    \
        *(float4*)(w2 + 4 * s_) = *(const float4*)&lds[2][LR][lc + 4 * s_];    \
        *(float4*)(u0 + 4 * s_) = *(const float4*)&lds[3][LR][lc + 4 * s_];    \
        *(float4*)(u1 + 4 * s_) = *(const float4*)&lds[4][LR][lc + 4 * s_];    \
    }

// accumulate 5x4 taps; window elem m <-> global col x0w+m, tap k = dx+j in [0,7]
#define COMPW()                                                                \
    _Pragma("unroll") for (int dx_ = 0; dx_ < 5; ++dx_)                        \
        _Pragma("unroll") for (int j_ = 0; j_ < 4; ++j_) {                     \
            const int k_ = dx_ + j_;                                           \
            const float d0_ = c0f[j_] - w0[k_];                                \
            const float d1_ = c1f[j_] - w1[k_];                                \
            const float d2_ = c2f[j_] - w2[k_];                                \
            float diff_ = d0_ * d0_;                                           \
            diff_ = fmaf(d1_, d1_, diff_);                                     \
            diff_ = fmaf(d2_, d2_, diff_);                                     \
            const float c_ = fmaxf(fmaf(diff_, -SIDIV, COEF0), 0.f);           \
            num0[j_] = fmaf(u0[k_], c_, num0[j_]);                             \
            num1[j_] = fmaf(u1[k_], c_, num1[j_]);                             \
            den[j_] += c_;                                                     \
        }

__global__ __launch_bounds__(256)
void jbf_mlp(const float* __restrict__ t, const float* __restrict__ v,
             float* __restrict__ out) {
    __shared__ float lds[5][TR][TC];        // 31,680 B -> 5 blocks/CU

    // ---- XCD-aware bijective swizzle: XCD i owns tiles [i*225, (i+1)*225) ----
    const int wgid = (blockIdx.x & (NXCD - 1)) * CPX + (blockIdx.x >> 3);
    const int n   = wgid / 900;             // image
    const int rem = wgid % 900;
    const int by  = rem / 10;               // tile-row (y-major band)
    const int bx  = rem % 10;
    const int gx0 = bx * 128;
    const int gy0 = by * 8;

    const float* tn = t + (size_t)n * 3 * HW;
    const float* vn = v + (size_t)n * 2 * HW;
    float*       on = out + (size_t)n * 2 * HW;

    const int tid = threadIdx.x;

    // ---------------- stage, phase 1: issue ALL global loads ----------------
    float4 vals[8];
#pragma unroll
    for (int it = 0; it < 8; ++it) {
        const int i = tid + it * 256;       // it<7 always < NCHUNK; it==7 needs guard
        const int k  = i % NK;
        const int rr = (i / NK) % TR;
        const int ch = i / (NK * TR);
        const int gy = gy0 - 2 + rr;
        const int gx = gx0 - 4 + 4 * k;
        vals[it] = make_float4(0.f, 0.f, 0.f, 0.f);
        const bool live = (it < 7 || i < NCHUNK) &&
                          ((unsigned)gy < (unsigned)H_) &&
                          ((unsigned)gx < (unsigned)(W_ - 3));
        if (live) {
            const float* src = (ch < 3) ? (tn + (size_t)ch * HW)
                                        : (vn + (size_t)(ch - 3) * HW);
            vals[it] = *(const float4*)(src + gy * W_ + gx);   // 8 independent loads
        }
    }

    // ---------------- stage, phase 2: all LDS writes ----------------
#pragma unroll
    for (int it = 0; it < 8; ++it) {
        const int i = tid + it * 256;
        if (it < 7 || i < NCHUNK) {
            const int k  = i % NK;
            const int rr = (i / NK) % TR;
            const int ch = i / (NK * TR);
            // global cols gx..gx+3 <-> staged cols 4k-2 .. 4k+1
            float* row = &lds[ch][rr][0];
            const float4 val = vals[it];
            if (k > 0)      *(float2*)&row[4 * k - 2] = make_float2(val.x, val.y);
            if (k < NK - 1) *(float2*)&row[4 * k]     = make_float2(val.z, val.w);
        }
    }
    __syncthreads();

    // ---------------- compute 4 px from LDS ----------------
    const int tx = tid & 31;                 // x-group within tile
    const int ty = tid >> 5;                 // output row within tile
    const int lc = 4 * tx;                   // window base staged col

    float c0f[4], c1f[4], c2f[4];
    float num0[4] = {0.f, 0.f, 0.f, 0.f};
    float num1[4] = {0.f, 0.f, 0.f, 0.f};
    float den[4]  = {0.f, 0.f, 0.f, 0.f};

    {   // r = 2 first: its window contains the centers (elem j+2 = pixel j)
        const int lr = ty + 2;
        LOADW(lr)
#pragma unroll
        for (int j = 0; j < 4; ++j) {
            c0f[j] = w0[j + 2];
            c1f[j] = w1[j + 2];
            c2f[j] = w2[j + 2];
        }
        COMPW()
    }
#pragma unroll 1
    for (int i = 0; i < 4; ++i) {
        const int r = i + (i >> 1);          // 0,1,3,4
        const int lr = ty + r;
        LOADW(lr)
        COMPW()
    }

    float4 o0, o1;
    float* o0a = (float*)&o0;
    float* o1a = (float*)&o1;
#pragma unroll
    for (int j = 0; j < 4; ++j) {
        const float rcp = 1.f / den[j];
        // mimic the reference's fp16 round-trip
        o0a[j] = __half2float(__float2half(num0[j] * rcp));
        o1a[j] = __half2float(__float2half(num1[j] * rcp));
    }
    const int ctr = (gy0 + ty) * W_ + gx0 + 4 * tx;
    *(float4*)(on + ctr) = o0;
    *(float4*)(on + HW + ctr) = o1;
}

extern "C" void kernel_launch(void* const* d_in, const int* in_sizes, int n_in,
                              void* d_out, int out_size, void* d_ws, size_t ws_size,
                              hipStream_t stream) {
    const float* t = (const float*)d_in[0];
    const float* v = (const float*)d_in[1];
    float* out = (float*)d_out;

    // 10 x-tiles * 90 y-tiles * 2 images = 1800 blocks of 256 (XCD-swizzled)
    jbf_mlp<<<1800, 256, 0, stream>>>(t, v, out);
}